// Round 5
// baseline (447.880 us; speedup 1.0000x reference)
//
#include <hip/hip_runtime.h>
#include <cstdint>
#include <cstddef>

typedef unsigned short u16;
typedef unsigned int   u32;

#define SEQ    2048
#define EDIM   2048
#define HEADS  16
#define DHEAD  128
#define CCH    128
#define NCH    16
#define TOKENS 4096   // B*S

typedef __attribute__((ext_vector_type(8))) short short8;
typedef __attribute__((ext_vector_type(4))) float floatx4;

__device__ __forceinline__ float b2f(u16 b) {
    u32 u = ((u32)b) << 16; float f; __builtin_memcpy(&f, &u, 4); return f;
}
__device__ __forceinline__ u16 f2b(float f) {
    u32 u; __builtin_memcpy(&u, &f, 4);
    u32 r = (u + 0x7fffu + ((u >> 16) & 1u)) >> 16;
    return (u16)r;
}
__device__ __forceinline__ void unpack8(uint4 u, float* f) {
    f[0] = b2f((u16)(u.x & 0xffff)); f[1] = b2f((u16)(u.x >> 16));
    f[2] = b2f((u16)(u.y & 0xffff)); f[3] = b2f((u16)(u.y >> 16));
    f[4] = b2f((u16)(u.z & 0xffff)); f[5] = b2f((u16)(u.z >> 16));
    f[6] = b2f((u16)(u.w & 0xffff)); f[7] = b2f((u16)(u.w >> 16));
}
__device__ __forceinline__ uint4 pack8(const float* f) {
    uint4 u;
    u.x = (u32)f2b(f[0]) | ((u32)f2b(f[1]) << 16);
    u.y = (u32)f2b(f[2]) | ((u32)f2b(f[3]) << 16);
    u.z = (u32)f2b(f[4]) | ((u32)f2b(f[5]) << 16);
    u.w = (u32)f2b(f[6]) | ((u32)f2b(f[7]) << 16);
    return u;
}

// async global->LDS, 16B per lane. LDS dest is wave-uniform base + lane*16.
__device__ __forceinline__ void gld_lds16(const u16* g, u16* l) {
    __builtin_amdgcn_global_load_lds((const __attribute__((address_space(1))) void*)g,
                                     (__attribute__((address_space(3))) void*)l, 16, 0, 0);
}
// raw barrier (no compiler-forced vmcnt(0) drain) + compiler-level reorder fences
#define CFENCE() __asm__ volatile("" ::: "memory")
#define RAW_BARRIER() do { CFENCE(); __builtin_amdgcn_s_barrier(); CFENCE(); } while (0)

// ---------------- fp32 -> bf16 bulk convert (4 elems/thread) ----------------
__global__ __launch_bounds__(256) void k_f32_to_bf16(const float* __restrict__ in,
                                                     u16* __restrict__ out) {
    int i = blockIdx.x * 256 + threadIdx.x;
    float4 v = ((const float4*)in)[i];
    uint2 o;
    o.x = (u32)f2b(v.x) | ((u32)f2b(v.y) << 16);
    o.y = (u32)f2b(v.z) | ((u32)f2b(v.w) << 16);
    ((uint2*)out)[i] = o;
}

// ------------- weight transpose+convert: W[k][n] fp32 -> Wt[n][k] bf16 -------------
__global__ void k_transW(const float* __restrict__ W0, const float* __restrict__ W1,
                         const float* __restrict__ W2, const float* __restrict__ W3,
                         const float* __restrict__ W4, u16* __restrict__ out) {
    const float* W;
    int z = blockIdx.z;
    switch (z) {
        case 0: W = W0; break; case 1: W = W1; break; case 2: W = W2; break;
        case 3: W = W3; break; default: W = W4; break;
    }
    __shared__ float tile[32][33];
    int n = blockIdx.x * 32 + threadIdx.x;
    int k = blockIdx.y * 32 + threadIdx.y;
    tile[threadIdx.y][threadIdx.x] = W[(size_t)k * EDIM + n];
    __syncthreads();
    int on = blockIdx.x * 32 + threadIdx.y;
    int ok = blockIdx.y * 32 + threadIdx.x;
    out[(size_t)z * EDIM * EDIM + (size_t)on * EDIM + ok] = f2b(tile[threadIdx.x][threadIdx.y]);
}

// ---------------- bf16 MFMA GEMM: C[m][n] = sum_k A[m][k] * Bt[n][k] ----------------
// 256x128 block tile, 4 waves each 128x64 (8x4 MFMA grid) -> 42.7 FLOP/LDS-byte.
// BK=32, double-buffered LDS, true-async pipeline (vmcnt(6) + raw s_barrier),
// XOR-swizzled staging: conflict-free frag reads.
__global__ __launch_bounds__(256, 2) void k_gemm(const u16* __restrict__ A,
                                                 const u16* __restrict__ Bt,
                                                 void* __restrict__ C,
                                                 int K, int N,
                                                 long long zstrB, long long zstrC,
                                                 int out_bf16, int mode,
                                                 u16* __restrict__ KdT,
                                                 u16* __restrict__ VT,
                                                 const float* __restrict__ slopes,
                                                 const float* __restrict__ mask) {
    __shared__ u16 As[2][256 * 32];
    __shared__ u16 Bs[2][128 * 32];
    int z = blockIdx.z;
    const u16* Bz = Bt + (size_t)z * (size_t)zstrB;
    int m0 = blockIdx.y * 256, n0 = blockIdx.x * 128;
    int tid = threadIdx.x;
    int w = tid >> 6, lane = tid & 63;
    int wr = w >> 1, wc = w & 1;          // wave: rows wr*128.., cols wc*64..
    int lrow = lane & 15, khalf = lane >> 4;

    floatx4 acc[8][4];
#pragma unroll
    for (int i = 0; i < 8; i++)
#pragma unroll
        for (int j = 0; j < 4; j++) acc[i][j] = (floatx4){0.f, 0.f, 0.f, 0.f};

    // staging: chunk c -> LDS row c>>2, slot c&3; slot holds logical granule
    // g = slot ^ ((row>>1)&3)  (swizzle -> conflict-free frag reads)
    const u16* aptr[4];
    const u16* bptr[2];
    int loffA[4], loffB[2];
#pragma unroll
    for (int i = 0; i < 4; i++) {
        int c = tid + i * 256;            // [0,1024): A tile 256 rows
        int row = c >> 2, slot = c & 3;
        int g = slot ^ ((row >> 1) & 3);
        aptr[i] = A + (size_t)(m0 + row) * K + g * 8;
        loffA[i] = c * 8;
    }
#pragma unroll
    for (int i = 0; i < 2; i++) {
        int c = tid + i * 256;            // [0,512): B tile 128 rows
        int row = c >> 2, slot = c & 3;
        int g = slot ^ ((row >> 1) & 3);
        bptr[i] = Bz + (size_t)(n0 + row) * K + g * 8;
        loffB[i] = c * 8;
    }
    // frag LDS offsets (u16 units): row*32 + (khalf ^ ((row>>1)&3))*8
    int aoff[8], boff[4];
#pragma unroll
    for (int i = 0; i < 8; i++) {
        int ra = wr * 128 + i * 16 + lrow;
        aoff[i] = ra * 32 + ((khalf ^ ((ra >> 1) & 3)) * 8);
    }
#pragma unroll
    for (int j = 0; j < 4; j++) {
        int rb = wc * 64 + j * 16 + lrow;
        boff[j] = rb * 32 + ((khalf ^ ((rb >> 1) & 3)) * 8);
    }

    int nIter = K >> 5;
    // prologue: tiles 0 and 1 in flight (12 outstanding loads/thread)
#pragma unroll
    for (int i = 0; i < 4; i++) gld_lds16(aptr[i] + 0,  &As[0][loffA[i]]);
#pragma unroll
    for (int i = 0; i < 2; i++) gld_lds16(bptr[i] + 0,  &Bs[0][loffB[i]]);
#pragma unroll
    for (int i = 0; i < 4; i++) gld_lds16(aptr[i] + 32, &As[1][loffA[i]]);
#pragma unroll
    for (int i = 0; i < 2; i++) gld_lds16(bptr[i] + 32, &Bs[1][loffB[i]]);

    for (int it = 0; it < nIter; ++it) {
        // wait only the oldest tile's 6 loads; keep next tile's 6 in flight
        if (it + 1 < nIter) __builtin_amdgcn_s_waitcnt(0xF76);  // vmcnt(6)
        else                __builtin_amdgcn_s_waitcnt(0xF70);  // vmcnt(0)
        RAW_BARRIER();
        int buf = it & 1;
        short8 af[8], bfr[4];
#pragma unroll
        for (int i = 0; i < 8; i++) af[i]  = *(const short8*)&As[buf][aoff[i]];
#pragma unroll
        for (int j = 0; j < 4; j++) bfr[j] = *(const short8*)&Bs[buf][boff[j]];
#pragma unroll
        for (int i = 0; i < 8; i++)
#pragma unroll
            for (int j = 0; j < 4; j++)
                acc[i][j] = __builtin_amdgcn_mfma_f32_16x16x32_bf16(af[i], bfr[j], acc[i][j], 0, 0, 0);
        RAW_BARRIER();   // all waves done reading buf; safe to overwrite (no vm drain)
        if (it + 2 < nIter) {
            int k0 = (it + 2) * 32;
#pragma unroll
            for (int i = 0; i < 4; i++) gld_lds16(aptr[i] + k0, &As[buf][loffA[i]]);
#pragma unroll
            for (int i = 0; i < 2; i++) gld_lds16(bptr[i] + k0, &Bs[buf][loffB[i]]);
        }
    }

    int writeVT  = (mode == 1 && z == 2);
    int writeKdT = (mode == 1 && z == 1);

    if (!writeVT) {
        size_t cz = (size_t)z * (size_t)zstrC;
#pragma unroll
        for (int i = 0; i < 8; i++)
#pragma unroll
            for (int j = 0; j < 4; j++) {
                int mrow = m0 + wr * 128 + i * 16 + khalf * 4;
                int ncol = n0 + wc * 64 + j * 16 + lrow;
#pragma unroll
                for (int r = 0; r < 4; r++) {
                    float val = acc[i][j][r];
                    if (out_bf16)
                        ((u16*)C)[cz + (size_t)(mrow + r) * N + ncol] = f2b(val);
                    else
                        ((float*)C)[cz + (size_t)(mrow + r) * N + ncol] = val;
                }
            }
    }
    if (writeVT || writeKdT) {
        // blockIdx.y covers 256 tokens = 2 chunks; wave row-half wr picks the chunk
        int b = blockIdx.y >> 3, h = blockIdx.x;
        int cc = ((blockIdx.y & 7) << 1) + wr;
        size_t tile = ((size_t)b * 256 + (size_t)h * 16 + (size_t)cc) * 16384;
        float s = slopes[h];
        u16* dst = (writeVT ? VT : KdT) + tile;
#pragma unroll
        for (int i = 0; i < 8; i++)
#pragma unroll
            for (int j = 0; j < 4; j++) {
                int t0 = i * 16 + khalf * 4;              // within-chunk token
                int d  = wc * 64 + j * 16 + lrow;
                u16 pk[4];
#pragma unroll
                for (int r = 0; r < 4; r++) {
                    int t = t0 + r;
                    float sc = writeVT ? mask[(size_t)b * SEQ + cc * CCH + t]
                                       : __expf(-s * (float)(CCH - t));
                    pk[r] = f2b(acc[i][j][r] * sc);
                }
                *(uint2*)&dst[(size_t)d * 128 + t0] = *(const uint2*)pk;
            }
    }
}

// ---------------- kvcT[e][d] = sum_t VT[e][t] * KdT[d][t] (MFMA, frags from L2) ----------------
__global__ __launch_bounds__(256) void k_kvc(const u16* __restrict__ VT,
                                             const u16* __restrict__ KdT,
                                             u16* __restrict__ kvT) {
    int bid = blockIdx.x, tid = threadIdx.x;
    int w = tid >> 6, lane = tid & 63;
    int wr = w >> 1, wc = w & 1;
    int lrow = lane & 15, khalf = lane >> 4;
    const u16* va = VT  + (size_t)bid * 16384;
    const u16* kb = KdT + (size_t)bid * 16384;
    floatx4 acc[4][4];
#pragma unroll
    for (int i = 0; i < 4; i++)
#pragma unroll
        for (int j = 0; j < 4; j++) acc[i][j] = (floatx4){0.f, 0.f, 0.f, 0.f};
#pragma unroll
    for (int kk = 0; kk < 4; kk++) {
        short8 a[4], bf[4];
#pragma unroll
        for (int i = 0; i < 4; i++)
            a[i] = *(const short8*)(va + (size_t)(wr * 64 + i * 16 + lrow) * 128 + kk * 32 + khalf * 8);
#pragma unroll
        for (int j = 0; j < 4; j++)
            bf[j] = *(const short8*)(kb + (size_t)(wc * 64 + j * 16 + lrow) * 128 + kk * 32 + khalf * 8);
#pragma unroll
        for (int i = 0; i < 4; i++)
#pragma unroll
            for (int j = 0; j < 4; j++)
                acc[i][j] = __builtin_amdgcn_mfma_f32_16x16x32_bf16(a[i], bf[j], acc[i][j], 0, 0, 0);
    }
    u16* o = kvT + (size_t)bid * 16384;
#pragma unroll
    for (int i = 0; i < 4; i++)
#pragma unroll
        for (int j = 0; j < 4; j++)
#pragma unroll
            for (int r = 0; r < 4; r++)
                o[(size_t)(wr * 64 + i * 16 + khalf * 4 + r) * 128 + wc * 64 + j * 16 + lrow] =
                    f2b(acc[i][j][r]);
}

// ---------------- pass A2: in-place decay scan over chunks ----------------
__global__ __launch_bounds__(256) void k_scan(u16* __restrict__ kvbuf,
                                              const float* __restrict__ slopes) {
    int gid = blockIdx.x * 256 + threadIdx.x;   // < 32*16384
    int idx = gid & 16383;
    int bh = gid >> 14;
    int h = bh & 15;
    float cd = __expf(-slopes[h] * (float)CCH);
    u16* p = kvbuf + (size_t)bh * NCH * 16384 + idx;
    float st = 0.f;
    for (int c = 0; c < NCH; c++) {
        float tmp = b2f(p[(size_t)c * 16384]);
        p[(size_t)c * 16384] = f2b(st);
        st = cd * st + tmp;
    }
}

// ---------------- pass B (MFMA): out = qdec*(Q @ stT^T) + (decay.S) @ V ----------------
__global__ __launch_bounds__(256) void k_attn_out(const u16* __restrict__ q,
                                                  const u16* __restrict__ k,
                                                  const u16* __restrict__ VT,
                                                  const u16* __restrict__ kvT,
                                                  const float* __restrict__ slopes,
                                                  u16* __restrict__ attn) {
    __shared__ u16 KS[128 * 136];   // stages K, then reused for S
    int bid = blockIdx.x;
    int c = bid & 15, h = (bid >> 4) & 15, b = bid >> 8;
    float s = slopes[h];
    int tid = threadIdx.x;
    int w = tid >> 6, lane = tid & 63;
    int wr = w >> 1, wc = w & 1;
    int lrow = lane & 15, khalf = lane >> 4;
    size_t tokbase = (size_t)(b * SEQ + c * CCH);

    {
        const u16* kg = k + tokbase * EDIM + h * DHEAD;
#pragma unroll
        for (int i = 0; i < 8; i++) {
            int cidx = tid + i * 256;
            int t = cidx >> 4, part = (cidx & 15) * 8;
            *(uint4*)&KS[t * 136 + part] = *(const uint4*)(kg + (size_t)t * EDIM + part);
        }
    }
    short8 qa[4][4];
    {
        const u16* qgbase = q + tokbase * EDIM + h * DHEAD;
#pragma unroll
        for (int i = 0; i < 4; i++) {
            const u16* qrow = qgbase + (size_t)(wr * 64 + i * 16 + lrow) * EDIM;
#pragma unroll
            for (int kk = 0; kk < 4; kk++)
                qa[i][kk] = *(const short8*)(qrow + kk * 32 + khalf * 8);
        }
    }
    __syncthreads();

    floatx4 acc[4][4];
#pragma unroll
    for (int i = 0; i < 4; i++)
#pragma unroll
        for (int j = 0; j < 4; j++) acc[i][j] = (floatx4){0.f, 0.f, 0.f, 0.f};
#pragma unroll
    for (int kk = 0; kk < 4; kk++) {
        short8 bf[4];
#pragma unroll
        for (int j = 0; j < 4; j++)
            bf[j] = *(const short8*)&KS[(wc * 64 + j * 16 + lrow) * 136 + kk * 32 + khalf * 8];
#pragma unroll
        for (int i = 0; i < 4; i++)
#pragma unroll
            for (int j = 0; j < 4; j++)
                acc[i][j] = __builtin_amdgcn_mfma_f32_16x16x32_bf16(qa[i][kk], bf[j], acc[i][j], 0, 0, 0);
    }
    __syncthreads();

#pragma unroll
    for (int i = 0; i < 4; i++)
#pragma unroll
        for (int j = 0; j < 4; j++) {
            int tbase = wr * 64 + i * 16 + khalf * 4;
            int u = wc * 64 + j * 16 + lrow;
#pragma unroll
            for (int r = 0; r < 4; r++) {
                int t = tbase + r;
                float val = (t >= u) ? acc[i][j][r] * __expf(-s * (float)(t - u)) : 0.f;
                KS[t * 136 + u] = f2b(val);
            }
        }
    __syncthreads();

#pragma unroll
    for (int i = 0; i < 4; i++)
#pragma unroll
        for (int j = 0; j < 4; j++) acc[i][j] = (floatx4){0.f, 0.f, 0.f, 0.f};
    const u16* st = kvT + (size_t)bid * 16384;
#pragma unroll
    for (int kk = 0; kk < 4; kk++) {
        short8 bf[4];
#pragma unroll
        for (int j = 0; j < 4; j++)
            bf[j] = *(const short8*)(st + (size_t)(wc * 64 + j * 16 + lrow) * 128 + kk * 32 + khalf * 8);
#pragma unroll
        for (int i = 0; i < 4; i++)
#pragma unroll
            for (int j = 0; j < 4; j++)
                acc[i][j] = __builtin_amdgcn_mfma_f32_16x16x32_bf16(qa[i][kk], bf[j], acc[i][j], 0, 0, 0);
    }
#pragma unroll
    for (int i = 0; i < 4; i++)
#pragma unroll
        for (int r = 0; r < 4; r++) {
            float qd = __expf(-s * (float)(wr * 64 + i * 16 + khalf * 4 + r));
#pragma unroll
            for (int j = 0; j < 4; j++) acc[i][j][r] *= qd;
        }
    const u16* vt = VT + (size_t)bid * 16384;
#pragma unroll
    for (int kk = 0; kk < 4; kk++) {
        short8 sa[4], bf[4];
#pragma unroll
        for (int i = 0; i < 4; i++)
            sa[i] = *(const short8*)&KS[(wr * 64 + i * 16 + lrow) * 136 + kk * 32 + khalf * 8];
#pragma unroll
        for (int j = 0; j < 4; j++)
            bf[j] = *(const short8*)(vt + (size_t)(wc * 64 + j * 16 + lrow) * 128 + kk * 32 + khalf * 8);
#pragma unroll
        for (int i = 0; i < 4; i++)
#pragma unroll
            for (int j = 0; j < 4; j++)
                acc[i][j] = __builtin_amdgcn_mfma_f32_16x16x32_bf16(sa[i], bf[j], acc[i][j], 0, 0, 0);
    }

    u16* og = attn + tokbase * EDIM + h * DHEAD;
#pragma unroll
    for (int i = 0; i < 4; i++)
#pragma unroll
        for (int j = 0; j < 4; j++)
#pragma unroll
            for (int r = 0; r < 4; r++)
                og[(size_t)(wr * 64 + i * 16 + khalf * 4 + r) * EDIM + wc * 64 + j * 16 + lrow] =
                    f2b(acc[i][j][r]);
}

// ---------------- RMSNorm over 2048 + sigmoid gate; writes bf16 gated ----------------
__global__ __launch_bounds__(256) void k_rms_gate(const u16* __restrict__ attn,
                                                  const u16* __restrict__ gpre,
                                                  const float* __restrict__ nw,
                                                  u16* __restrict__ out) {
    int n = blockIdx.x, tid = threadIdx.x;
    float a[8];
    unpack8(((const uint4*)(attn + (size_t)n * EDIM))[tid], a);
    float ss = 0.f;
#pragma unroll
    for (int j = 0; j < 8; j++) ss += a[j] * a[j];
#pragma unroll
    for (int o = 32; o > 0; o >>= 1) ss += __shfl_down(ss, o, 64);
    __shared__ float red[5];
    int w = tid >> 6, lane = tid & 63;
    if (lane == 0) red[w] = ss;
    __syncthreads();
    if (tid == 0) red[4] = rsqrtf((red[0] + red[1] + red[2] + red[3]) / 2048.f + 1e-6f);
    __syncthreads();
    float rs = red[4];
    float g[8];
    unpack8(((const uint4*)(gpre + (size_t)n * EDIM))[tid], g);
    const float4* np4 = (const float4*)(nw + tid * 8);
    float4 w0 = np4[0], w1 = np4[1];
    float wv[8] = {w0.x, w0.y, w0.z, w0.w, w1.x, w1.y, w1.z, w1.w};
    float o8[8];
#pragma unroll
    for (int j = 0; j < 8; j++) {
        float sg = 1.f / (1.f + __expf(-g[j]));
        o8[j] = sg * (a[j] * rs * wv[j]);
    }
    ((uint4*)(out + (size_t)n * EDIM))[tid] = pack8(o8);
}

extern "C" void kernel_launch(void* const* d_in, const int* in_sizes, int n_in,
                              void* d_out, int out_size, void* d_ws, size_t ws_size,
                              hipStream_t stream) {
    const float* hs     = (const float*)d_in[0];
    const float* mask   = (const float*)d_in[1];
    const float* slopes = (const float*)d_in[2];
    const float* Wq     = (const float*)d_in[3];
    const float* Wk     = (const float*)d_in[4];
    const float* Wv     = (const float*)d_in[5];
    const float* Wg     = (const float*)d_in[6];
    const float* Wo     = (const float*)d_in[7];
    const float* nw     = (const float*)d_in[8];
    float* out = (float*)d_out;

    char* ws = (char*)d_ws;
    u16* hsb   = (u16*)ws;                     // hs bf16 -> later gated
    u16* Wt    = (u16*)(ws + 16777216LL);      // 5 x 4M elems bf16
    u16* qkvg  = (u16*)(ws + 58720256LL);      // q, k, VT(v slot), g
    u16* kvbuf = (u16*)(ws + 125829120LL);     // 8M elems (stT tiles)
    u16* attn  = (u16*)(ws + 142606336LL);     // first KdT, then attn output
    u16* qb  = qkvg;
    u16* kb  = qkvg + 8388608LL;
    u16* VT  = qkvg + 16777216LL;              // written by fused gemm epilogue (z==2)
    u16* gb  = qkvg + 25165824LL;
    u16* KdT = attn;                           // alias (kvc consumes before attn_out writes)

    k_f32_to_bf16<<<8192, 256, 0, stream>>>(hs, hsb);
    k_transW<<<dim3(64, 64, 5), dim3(32, 32, 1), 0, stream>>>(Wq, Wk, Wv, Wg, Wo, Wt);
    k_gemm<<<dim3(16, 16, 4), 256, 0, stream>>>(hsb, Wt, qkvg, EDIM, EDIM,
                                                (long long)EDIM * EDIM,
                                                (long long)TOKENS * EDIM, 1,
                                                1, KdT, VT, slopes, mask);
    k_kvc<<<512, 256, 0, stream>>>(VT, KdT, kvbuf);
    k_scan<<<2048, 256, 0, stream>>>(kvbuf, slopes);
    k_attn_out<<<512, 256, 0, stream>>>(qb, kb, VT, kvbuf, slopes, attn);
    k_rms_gate<<<TOKENS, 256, 0, stream>>>(attn, gb, nw, hsb);
    k_gemm<<<dim3(16, 16, 1), 256, 0, stream>>>(hsb, Wt + 4LL * 4194304LL, out, EDIM, EDIM,
                                                0LL, 0LL, 0,
                                                0, (u16*)nullptr, (u16*)nullptr, slopes, mask);
}

// Round 7
// 424.195 us; speedup vs baseline: 1.0558x; 1.0558x over previous
//
#include <hip/hip_runtime.h>
#include <cstdint>
#include <cstddef>

typedef unsigned short u16;
typedef unsigned int   u32;

#define SEQ    2048
#define EDIM   2048
#define HEADS  16
#define DHEAD  128
#define CCH    128
#define NCH    16
#define TOKENS 4096   // B*S

typedef __attribute__((ext_vector_type(8))) short short8;
typedef __attribute__((ext_vector_type(4))) float floatx4;

__device__ __forceinline__ float b2f(u16 b) {
    u32 u = ((u32)b) << 16; float f; __builtin_memcpy(&f, &u, 4); return f;
}
__device__ __forceinline__ u16 f2b(float f) {
    u32 u; __builtin_memcpy(&u, &f, 4);
    u32 r = (u + 0x7fffu + ((u >> 16) & 1u)) >> 16;
    return (u16)r;
}
__device__ __forceinline__ void unpack8(uint4 u, float* f) {
    f[0] = b2f((u16)(u.x & 0xffff)); f[1] = b2f((u16)(u.x >> 16));
    f[2] = b2f((u16)(u.y & 0xffff)); f[3] = b2f((u16)(u.y >> 16));
    f[4] = b2f((u16)(u.z & 0xffff)); f[5] = b2f((u16)(u.z >> 16));
    f[6] = b2f((u16)(u.w & 0xffff)); f[7] = b2f((u16)(u.w >> 16));
}
__device__ __forceinline__ uint4 pack8(const float* f) {
    uint4 u;
    u.x = (u32)f2b(f[0]) | ((u32)f2b(f[1]) << 16);
    u.y = (u32)f2b(f[2]) | ((u32)f2b(f[3]) << 16);
    u.z = (u32)f2b(f[4]) | ((u32)f2b(f[5]) << 16);
    u.w = (u32)f2b(f[6]) | ((u32)f2b(f[7]) << 16);
    return u;
}

// async global->LDS, 16B per lane. LDS dest is wave-uniform base + lane*16.
__device__ __forceinline__ void gld_lds16(const u16* g, u16* l) {
    __builtin_amdgcn_global_load_lds((const __attribute__((address_space(1))) void*)g,
                                     (__attribute__((address_space(3))) void*)l, 16, 0, 0);
}
// raw barrier (no compiler-forced vmcnt(0) drain) + compiler-level reorder fences
#define CFENCE() __asm__ volatile("" ::: "memory")
#define RAW_BARRIER() do { CFENCE(); __builtin_amdgcn_s_barrier(); CFENCE(); } while (0)

// fragment-major weight layout: for column group g16=n>>4 and k-block kb=k>>5,
// one wave's B-frag (64 lanes x 16B) is contiguous:
// off = g16*(16*K) + kb*512 + khalf*128 + lrow*8 + (k&7), khalf=(k>>3)&3, lrow=n&15
__device__ __forceinline__ size_t wfrag_off(int n, int k) {
    return (size_t)(n >> 4) * (16 * EDIM) + (size_t)(k >> 5) * 512 +
           (size_t)(((k >> 3) & 3) * 128 + (n & 15) * 8 + (k & 7));
}

// ---------------- fp32 -> bf16 bulk convert (4 elems/thread) ----------------
__global__ __launch_bounds__(256) void k_f32_to_bf16(const float* __restrict__ in,
                                                     u16* __restrict__ out) {
    int i = blockIdx.x * 256 + threadIdx.x;
    float4 v = ((const float4*)in)[i];
    uint2 o;
    o.x = (u32)f2b(v.x) | ((u32)f2b(v.y) << 16);
    o.y = (u32)f2b(v.z) | ((u32)f2b(v.w) << 16);
    ((uint2*)out)[i] = o;
}

// ------- weight convert: W[k][n] fp32 -> fragment-major bf16 (see wfrag_off) -------
__global__ void k_transW(const float* __restrict__ W0, const float* __restrict__ W1,
                         const float* __restrict__ W2, const float* __restrict__ W3,
                         const float* __restrict__ W4, u16* __restrict__ out) {
    const float* W;
    int z = blockIdx.z;
    switch (z) {
        case 0: W = W0; break; case 1: W = W1; break; case 2: W = W2; break;
        case 3: W = W3; break; default: W = W4; break;
    }
    __shared__ float tile[32][33];
    int n = blockIdx.x * 32 + threadIdx.x;
    int k = blockIdx.y * 32 + threadIdx.y;
    tile[threadIdx.y][threadIdx.x] = W[(size_t)k * EDIM + n];
    __syncthreads();
    int on = blockIdx.x * 32 + threadIdx.y;
    int ok = blockIdx.y * 32 + threadIdx.x;
    out[(size_t)z * EDIM * EDIM + wfrag_off(on, ok)] = f2b(tile[threadIdx.x][threadIdx.y]);
}

// ---------------- bf16 MFMA GEMM: C[m][n] = sum_k A[m][k] * B[k][n] ----------------
// 128x128 tile. A: DMA->LDS double-buffered (XOR swizzle, conflict-free).
// B: fragment-major weights streamed DIRECTLY from L2 into registers with
// 1-iter prefetch (no LDS). Raw barriers + manual vmcnt keep 2 A-tiles +
// B-prefetch in flight across barriers. VMC must be a literal constant:
// main loop vmcnt(6)=0xF76 (queue [DMA(it)2, B(it)4, DMA(it+1)2]);
// final step vmcnt(4)=0xF74 (queue [DMA(last)2, B(last)4]).
#define GEMM_STEP(IT, BUF, BCUR, BNEXT, VMC)                                    \
  {                                                                             \
    __builtin_amdgcn_s_waitcnt(VMC);                                            \
    RAW_BARRIER();                                                              \
    short8 af[4];                                                               \
    _Pragma("unroll")                                                           \
    for (int i = 0; i < 4; i++) af[i] = *(const short8*)&As[BUF][aoff[i]];      \
    if ((IT) + 1 < nIter) {                                                     \
      int kb = ((IT) + 1) * 512;                                                \
      _Pragma("unroll")                                                         \
      for (int j = 0; j < 4; j++)                                               \
        BNEXT[j] = *(const short8*)(bBase[j] + kb);                             \
    }                                                                           \
    _Pragma("unroll")                                                           \
    for (int i = 0; i < 4; i++)                                                 \
      _Pragma("unroll")                                                         \
      for (int j = 0; j < 4; j++)                                               \
        acc[i][j] = __builtin_amdgcn_mfma_f32_16x16x32_bf16(af[i], BCUR[j],     \
                                                            acc[i][j], 0, 0, 0);\
    RAW_BARRIER();                                                              \
    if ((IT) + 2 < nIter) {                                                     \
      int k0 = ((IT) + 2) * 32;                                                 \
      _Pragma("unroll")                                                         \
      for (int i = 0; i < 2; i++) gld_lds16(aptr[i] + k0, &As[BUF][loffA[i]]);  \
    }                                                                           \
  }

__global__ __launch_bounds__(256, 3) void k_gemm(const u16* __restrict__ A,
                                                 const u16* __restrict__ Bt,
                                                 void* __restrict__ C,
                                                 int K, int N,
                                                 long long zstrB, long long zstrC,
                                                 int out_bf16, int mode,
                                                 u16* __restrict__ KdT,
                                                 u16* __restrict__ VT,
                                                 const float* __restrict__ slopes,
                                                 const float* __restrict__ mask) {
    __shared__ u16 As[2][128 * 32];
    int z = blockIdx.z;
    const u16* Bz = Bt + (size_t)z * (size_t)zstrB;
    int m0 = blockIdx.y * 128, n0 = blockIdx.x * 128;
    int tid = threadIdx.x;
    int w = tid >> 6, lane = tid & 63;
    int wr = w >> 1, wc = w & 1;
    int lrow = lane & 15, khalf = lane >> 4;

    floatx4 acc[4][4];
#pragma unroll
    for (int i = 0; i < 4; i++)
#pragma unroll
        for (int j = 0; j < 4; j++) acc[i][j] = (floatx4){0.f, 0.f, 0.f, 0.f};

    // A staging: chunk c in [0,512) -> LDS row c>>2, slot c&3; slot holds logical
    // granule g = slot ^ ((row>>1)&3)  (swizzle -> conflict-free frag reads)
    const u16* aptr[2];
    int loffA[2];
#pragma unroll
    for (int i = 0; i < 2; i++) {
        int c = tid + i * 256;
        int row = c >> 2, slot = c & 3;
        int g = slot ^ ((row >> 1) & 3);
        aptr[i] = A + (size_t)(m0 + row) * K + g * 8;
        loffA[i] = c * 8;
    }
    // A frag LDS offsets (u16 units): row*32 + (khalf ^ ((row>>1)&3))*8
    int aoff[4];
#pragma unroll
    for (int i = 0; i < 4; i++) {
        int ra = wr * 64 + i * 16 + lrow;
        aoff[i] = ra * 32 + ((khalf ^ ((ra >> 1) & 3)) * 8);
    }
    // B frag bases (fragment-major layout): coalesced 1KB wave loads
    const u16* bBase[4];
#pragma unroll
    for (int j = 0; j < 4; j++) {
        int g16 = (n0 + wc * 64 + j * 16) >> 4;
        bBase[j] = Bz + (size_t)g16 * (16 * (size_t)K) + khalf * 128 + lrow * 8;
    }

    int nIter = K >> 5;   // K=2048 -> 64 (even)
    // prologue: A tiles 0,1 via DMA (order pinned by CFENCE), then B frag 0
#pragma unroll
    for (int i = 0; i < 2; i++) gld_lds16(aptr[i] + 0,  &As[0][loffA[i]]);
#pragma unroll
    for (int i = 0; i < 2; i++) gld_lds16(aptr[i] + 32, &As[1][loffA[i]]);
    CFENCE();
    short8 bA[4], bB[4];
#pragma unroll
    for (int j = 0; j < 4; j++) bA[j] = *(const short8*)(bBase[j]);

    int it = 0;
    for (; it + 3 < nIter; it += 2) {
        GEMM_STEP(it,     0, bA, bB, 0xF76);   // vmcnt(6)
        GEMM_STEP(it + 1, 1, bB, bA, 0xF76);   // vmcnt(6)
    }
    // peeled tail (nIter even): steps nIter-2, nIter-1 with literal vmcnt
    GEMM_STEP(it,     0, bA, bB, 0xF76);       // vmcnt(6)
    GEMM_STEP(it + 1, 1, bB, bA, 0xF74);       // vmcnt(4)

    int writeVT  = (mode == 1 && z == 2);
    int writeKdT = (mode == 1 && z == 1);

    if (!writeVT) {
        size_t cz = (size_t)z * (size_t)zstrC;
#pragma unroll
        for (int i = 0; i < 4; i++)
#pragma unroll
            for (int j = 0; j < 4; j++) {
                int mrow = m0 + wr * 64 + i * 16 + khalf * 4;
                int ncol = n0 + wc * 64 + j * 16 + lrow;
#pragma unroll
                for (int r = 0; r < 4; r++) {
                    float val = acc[i][j][r];
                    if (out_bf16)
                        ((u16*)C)[cz + (size_t)(mrow + r) * N + ncol] = f2b(val);
                    else
                        ((float*)C)[cz + (size_t)(mrow + r) * N + ncol] = val;
                }
            }
    }
    if (writeVT || writeKdT) {
        int b = blockIdx.y >> 4, cc = blockIdx.y & 15, h = blockIdx.x;
        size_t tile = ((size_t)b * 256 + (size_t)h * 16 + (size_t)cc) * 16384;
        float s = slopes[h];
        u16* dst = (writeVT ? VT : KdT) + tile;
#pragma unroll
        for (int i = 0; i < 4; i++)
#pragma unroll
            for (int j = 0; j < 4; j++) {
                int t0 = wr * 64 + i * 16 + khalf * 4;
                int d  = wc * 64 + j * 16 + lrow;
                u16 pk[4];
#pragma unroll
                for (int r = 0; r < 4; r++) {
                    int t = t0 + r;
                    float sc = writeVT ? mask[(size_t)b * SEQ + cc * CCH + t]
                                       : __expf(-s * (float)(CCH - t));
                    pk[r] = f2b(acc[i][j][r] * sc);
                }
                *(uint2*)&dst[(size_t)d * 128 + t0] = *(const uint2*)pk;
            }
    }
}

// ---------------- kvcT[e][d] = sum_t VT[e][t] * KdT[d][t] (MFMA, frags from L2) ----------------
__global__ __launch_bounds__(256) void k_kvc(const u16* __restrict__ VT,
                                             const u16* __restrict__ KdT,
                                             u16* __restrict__ kvT) {
    int bid = blockIdx.x, tid = threadIdx.x;
    int w = tid >> 6, lane = tid & 63;
    int wr = w >> 1, wc = w & 1;
    int lrow = lane & 15, khalf = lane >> 4;
    const u16* va = VT  + (size_t)bid * 16384;
    const u16* kb = KdT + (size_t)bid * 16384;
    floatx4 acc[4][4];
#pragma unroll
    for (int i = 0; i < 4; i++)
#pragma unroll
        for (int j = 0; j < 4; j++) acc[i][j] = (floatx4){0.f, 0.f, 0.f, 0.f};
#pragma unroll
    for (int kk = 0; kk < 4; kk++) {
        short8 a[4], bf[4];
#pragma unroll
        for (int i = 0; i < 4; i++)
            a[i] = *(const short8*)(va + (size_t)(wr * 64 + i * 16 + lrow) * 128 + kk * 32 + khalf * 8);
#pragma unroll
        for (int j = 0; j < 4; j++)
            bf[j] = *(const short8*)(kb + (size_t)(wc * 64 + j * 16 + lrow) * 128 + kk * 32 + khalf * 8);
#pragma unroll
        for (int i = 0; i < 4; i++)
#pragma unroll
            for (int j = 0; j < 4; j++)
                acc[i][j] = __builtin_amdgcn_mfma_f32_16x16x32_bf16(a[i], bf[j], acc[i][j], 0, 0, 0);
    }
    u16* o = kvT + (size_t)bid * 16384;
#pragma unroll
    for (int i = 0; i < 4; i++)
#pragma unroll
        for (int j = 0; j < 4; j++)
#pragma unroll
            for (int r = 0; r < 4; r++)
                o[(size_t)(wr * 64 + i * 16 + khalf * 4 + r) * 128 + wc * 64 + j * 16 + lrow] =
                    f2b(acc[i][j][r]);
}

// ---------------- pass A2: in-place decay scan over chunks ----------------
__global__ __launch_bounds__(256) void k_scan(u16* __restrict__ kvbuf,
                                              const float* __restrict__ slopes) {
    int gid = blockIdx.x * 256 + threadIdx.x;   // < 32*16384
    int idx = gid & 16383;
    int bh = gid >> 14;
    int h = bh & 15;
    float cd = __expf(-slopes[h] * (float)CCH);
    u16* p = kvbuf + (size_t)bh * NCH * 16384 + idx;
    float st = 0.f;
    for (int c = 0; c < NCH; c++) {
        float tmp = b2f(p[(size_t)c * 16384]);
        p[(size_t)c * 16384] = f2b(st);
        st = cd * st + tmp;
    }
}

// ---------------- pass B (MFMA): out = qdec*(Q @ stT^T) + (decay.S) @ V ----------------
__global__ __launch_bounds__(256) void k_attn_out(const u16* __restrict__ q,
                                                  const u16* __restrict__ k,
                                                  const u16* __restrict__ VT,
                                                  const u16* __restrict__ kvT,
                                                  const float* __restrict__ slopes,
                                                  u16* __restrict__ attn) {
    __shared__ u16 KS[128 * 136];   // stages K, then reused for S
    int bid = blockIdx.x;
    int c = bid & 15, h = (bid >> 4) & 15, b = bid >> 8;
    float s = slopes[h];
    int tid = threadIdx.x;
    int w = tid >> 6, lane = tid & 63;
    int wr = w >> 1, wc = w & 1;
    int lrow = lane & 15, khalf = lane >> 4;
    size_t tokbase = (size_t)(b * SEQ + c * CCH);

    {
        const u16* kg = k + tokbase * EDIM + h * DHEAD;
#pragma unroll
        for (int i = 0; i < 8; i++) {
            int cidx = tid + i * 256;
            int t = cidx >> 4, part = (cidx & 15) * 8;
            *(uint4*)&KS[t * 136 + part] = *(const uint4*)(kg + (size_t)t * EDIM + part);
        }
    }
    short8 qa[4][4];
    {
        const u16* qgbase = q + tokbase * EDIM + h * DHEAD;
#pragma unroll
        for (int i = 0; i < 4; i++) {
            const u16* qrow = qgbase + (size_t)(wr * 64 + i * 16 + lrow) * EDIM;
#pragma unroll
            for (int kk = 0; kk < 4; kk++)
                qa[i][kk] = *(const short8*)(qrow + kk * 32 + khalf * 8);
        }
    }
    __syncthreads();

    floatx4 acc[4][4];
#pragma unroll
    for (int i = 0; i < 4; i++)
#pragma unroll
        for (int j = 0; j < 4; j++) acc[i][j] = (floatx4){0.f, 0.f, 0.f, 0.f};
#pragma unroll
    for (int kk = 0; kk < 4; kk++) {
        short8 bf[4];
#pragma unroll
        for (int j = 0; j < 4; j++)
            bf[j] = *(const short8*)&KS[(wc * 64 + j * 16 + lrow) * 136 + kk * 32 + khalf * 8];
#pragma unroll
        for (int i = 0; i < 4; i++)
#pragma unroll
            for (int j = 0; j < 4; j++)
                acc[i][j] = __builtin_amdgcn_mfma_f32_16x16x32_bf16(qa[i][kk], bf[j], acc[i][j], 0, 0, 0);
    }
    __syncthreads();

#pragma unroll
    for (int i = 0; i < 4; i++)
#pragma unroll
        for (int j = 0; j < 4; j++) {
            int tbase = wr * 64 + i * 16 + khalf * 4;
            int u = wc * 64 + j * 16 + lrow;
#pragma unroll
            for (int r = 0; r < 4; r++) {
                int t = tbase + r;
                float val = (t >= u) ? acc[i][j][r] * __expf(-s * (float)(t - u)) : 0.f;
                KS[t * 136 + u] = f2b(val);
            }
        }
    __syncthreads();

#pragma unroll
    for (int i = 0; i < 4; i++)
#pragma unroll
        for (int j = 0; j < 4; j++) acc[i][j] = (floatx4){0.f, 0.f, 0.f, 0.f};
    const u16* st = kvT + (size_t)bid * 16384;
#pragma unroll
    for (int kk = 0; kk < 4; kk++) {
        short8 bf[4];
#pragma unroll
        for (int j = 0; j < 4; j++)
            bf[j] = *(const short8*)(st + (size_t)(wc * 64 + j * 16 + lrow) * 128 + kk * 32 + khalf * 8);
#pragma unroll
        for (int i = 0; i < 4; i++)
#pragma unroll
            for (int j = 0; j < 4; j++)
                acc[i][j] = __builtin_amdgcn_mfma_f32_16x16x32_bf16(qa[i][kk], bf[j], acc[i][j], 0, 0, 0);
    }
#pragma unroll
    for (int i = 0; i < 4; i++)
#pragma unroll
        for (int r = 0; r < 4; r++) {
            float qd = __expf(-s * (float)(wr * 64 + i * 16 + khalf * 4 + r));
#pragma unroll
            for (int j = 0; j < 4; j++) acc[i][j][r] *= qd;
        }
    const u16* vt = VT + (size_t)bid * 16384;
#pragma unroll
    for (int kk = 0; kk < 4; kk++) {
        short8 sa[4], bf[4];
#pragma unroll
        for (int i = 0; i < 4; i++)
            sa[i] = *(const short8*)&KS[(wr * 64 + i * 16 + lrow) * 136 + kk * 32 + khalf * 8];
#pragma unroll
        for (int j = 0; j < 4; j++)
            bf[j] = *(const short8*)(vt + (size_t)(wc * 64 + j * 16 + lrow) * 128 + kk * 32 + khalf * 8);
#pragma unroll
        for (int i = 0; i < 4; i++)
#pragma unroll
            for (int j = 0; j < 4; j++)
                acc[i][j] = __builtin_amdgcn_mfma_f32_16x16x32_bf16(sa[i], bf[j], acc[i][j], 0, 0, 0);
    }

    u16* og = attn + tokbase * EDIM + h * DHEAD;
#pragma unroll
    for (int i = 0; i < 4; i++)
#pragma unroll
        for (int j = 0; j < 4; j++)
#pragma unroll
            for (int r = 0; r < 4; r++)
                og[(size_t)(wr * 64 + i * 16 + khalf * 4 + r) * EDIM + wc * 64 + j * 16 + lrow] =
                    f2b(acc[i][j][r]);
}

// ---------------- RMSNorm over 2048 + sigmoid gate; writes bf16 gated ----------------
__global__ __launch_bounds__(256) void k_rms_gate(const u16* __restrict__ attn,
                                                  const u16* __restrict__ gpre,
                                                  const float* __restrict__ nw,
                                                  u16* __restrict__ out) {
    int n = blockIdx.x, tid = threadIdx.x;
    float a[8];
    unpack8(((const uint4*)(attn + (size_t)n * EDIM))[tid], a);
    float ss = 0.f;
#pragma unroll
    for (int j = 0; j < 8; j++) ss += a[j] * a[j];
#pragma unroll
    for (int o = 32; o > 0; o >>= 1) ss += __shfl_down(ss, o, 64);
    __shared__ float red[5];
    int w = tid >> 6, lane = tid & 63;
    if (lane == 0) red[w] = ss;
    __syncthreads();
    if (tid == 0) red[4] = rsqrtf((red[0] + red[1] + red[2] + red[3]) / 2048.f + 1e-6f);
    __syncthreads();
    float rs = red[4];
    float g[8];
    unpack8(((const uint4*)(gpre + (size_t)n * EDIM))[tid], g);
    const float4* np4 = (const float4*)(nw + tid * 8);
    float4 w0 = np4[0], w1 = np4[1];
    float wv[8] = {w0.x, w0.y, w0.z, w0.w, w1.x, w1.y, w1.z, w1.w};
    float o8[8];
#pragma unroll
    for (int j = 0; j < 8; j++) {
        float sg = 1.f / (1.f + __expf(-g[j]));
        o8[j] = sg * (a[j] * rs * wv[j]);
    }
    ((uint4*)(out + (size_t)n * EDIM))[tid] = pack8(o8);
}

extern "C" void kernel_launch(void* const* d_in, const int* in_sizes, int n_in,
                              void* d_out, int out_size, void* d_ws, size_t ws_size,
                              hipStream_t stream) {
    const float* hs     = (const float*)d_in[0];
    const float* mask   = (const float*)d_in[1];
    const float* slopes = (const float*)d_in[2];
    const float* Wq     = (const float*)d_in[3];
    const float* Wk     = (const float*)d_in[4];
    const float* Wv     = (const float*)d_in[5];
    const float* Wg     = (const float*)d_in[6];
    const float* Wo     = (const float*)d_in[7];
    const float* nw     = (const float*)d_in[8];
    float* out = (float*)d_out;

    char* ws = (char*)d_ws;
    u16* hsb   = (u16*)ws;                     // hs bf16 -> later gated
    u16* Wt    = (u16*)(ws + 16777216LL);      // 5 x 4M elems bf16 (fragment-major)
    u16* qkvg  = (u16*)(ws + 58720256LL);      // q, k, VT(v slot), g
    u16* kvbuf = (u16*)(ws + 125829120LL);     // 8M elems (stT tiles)
    u16* attn  = (u16*)(ws + 142606336LL);     // first KdT, then attn output
    u16* qb  = qkvg;
    u16* kb  = qkvg + 8388608LL;
    u16* VT  = qkvg + 16777216LL;              // written by fused gemm epilogue (z==2)
    u16* gb  = qkvg + 25165824LL;
    u16* KdT = attn;                           // alias (kvc consumes before attn_out writes)

    k_f32_to_bf16<<<8192, 256, 0, stream>>>(hs, hsb);
    k_transW<<<dim3(64, 64, 5), dim3(32, 32, 1), 0, stream>>>(Wq, Wk, Wv, Wg, Wo, Wt);
    k_gemm<<<dim3(16, 32, 4), 256, 0, stream>>>(hsb, Wt, qkvg, EDIM, EDIM,
                                                (long long)EDIM * EDIM,
                                                (long long)TOKENS * EDIM, 1,
                                                1, KdT, VT, slopes, mask);
    k_kvc<<<512, 256, 0, stream>>>(VT, KdT, kvbuf);
    k_scan<<<2048, 256, 0, stream>>>(kvbuf, slopes);
    k_attn_out<<<512, 256, 0, stream>>>(qb, kb, VT, kvbuf, slopes, attn);
    k_rms_gate<<<TOKENS, 256, 0, stream>>>(attn, gb, nw, hsb);
    k_gemm<<<dim3(16, 32, 1), 256, 0, stream>>>(hsb, Wt + 4LL * 4194304LL, out, EDIM, EDIM,
                                                0LL, 0LL, 0,
                                                0, (u16*)nullptr, (u16*)nullptr, slopes, mask);
}